// Round 18
// baseline (565.867 us; speedup 1.0000x reference)
//
#include <hip/hip_runtime.h>

#define NS 32   // n_state
#define NI 16   // n_input
#define NA 48   // n_all
#define TT 64   // horizon
#define HT 32   // half horizon
#define CSZ (NA * NA)      // 2304 floats per C_t
#define NTRI 528           // upper-triangle pairs of 32x32

// ---------------- FAST PATH ----------------
// r17 base (best: 543 us) + ONE change: 512 threads (8 waves = 2/SIMD) with
// work redistributed at per-thread ILP >= 3. Mechanism: 1 wave/SIMD left
// ~79% of cycles as exposed LDS latency (VALUBusy 0.084% = ~21% of one CU);
// a second wave per SIMD hides it. r14's regression was ILP-1 at 4 waves —
// here ILP stays >= 3.
// Numerics bit-identical to r17: f64 state/intermediates, f32 A/B in LDS,
// exact-rcp shfl GJ in wave 0, symmetric-by-construction triangle P update
// (REQUIRED — asymmetric recursion diverges, 126976 signature), 4 barriers,
// K_t/P_t f32 to d_ws, barrier forward rollout, parallel mu pass, f32 out.
__launch_bounds__(512, 1)
__global__ void lqr_fast(const float* __restrict__ Ag,
                         const float* __restrict__ Bg,
                         const float* __restrict__ Cg,
                         const float* __restrict__ x0g,
                         float* __restrict__ out,
                         float* __restrict__ Kall,   // [TT][NI][NS] f32
                         float* __restrict__ Pall)   // [TT][NS][NS] f32
{
    __shared__ float  sXT[TT][NS];      //  8192 B  x trajectory (f32)
    __shared__ float  sA[NS][33];       //  4224 B  A as f32 (exact input data)
    __shared__ float  sB[NS][17];       //  2176 B  B as f32 (exact input data)
    __shared__ double sP[NS][33];       //  8448 B  Riccati state (f64)
    __shared__ double sPA[NS][33];      //  8448 B  P*A
    __shared__ double sPB[NS][17];      //  4352 B  P*B
    __shared__ double sHs[NI][33];      //  4224 B  S^T + B^T P A
    __shared__ double sKt[NI][33];      //  4224 B  K_t (f64)
    __shared__ double sGi[NI][17];      //  2176 B  G^{-1}
    __shared__ double sPp[NS][33];      //  8448 B  Q + A^T P A (symmetric)
    __shared__ short  sTri[NTRI];       //  1056 B  packed (i<<8)|j, i<=j
    __shared__ double sx[2][NS];        //   512 B
    __shared__ double su[NI];           //   128 B   (~56 KB)

    const int tid  = threadIdx.x;
    const int wid  = tid >> 6, lane = tid & 63;
    // phase-1 roles (512 threads): 16 threads/row, 2 PA cols + 1 PB col each
    const int pi   = tid >> 4;              // 0..31
    const int pj0  = (tid & 15) * 2;        // 0,2,..,30
    const int pb   = tid & 15;              // 0..15
    // phase-3 roles (first 256 threads)
    const int ki   = tid >> 4, kj0 = (tid & 15) * 2;

    for (int idx = tid; idx < NS * NS; idx += 512) {
        sA[idx >> 5][idx & 31] = Ag[idx];
        sP[idx >> 5][idx & 31] = 0.0;
    }
    for (int idx = tid; idx < NS * NI; idx += 512)
        sB[idx >> 4][idx & 15] = Bg[idx];
    // build upper-triangle (i,j) table once
    for (int e = tid; e < NTRI; e += 512) {
        int i = 0, rem = e;
        while (rem >= NS - i) { rem -= NS - i; ++i; }
        sTri[e] = (short)((i << 8) | (i + rem));
    }
    __syncthreads();

    // ---- backward sweep: 64 steps, 4 barriers each ----
    for (int t = TT - 1; t >= 0; --t) {
        const float* Ct = Cg + t * CSZ;

        // phase 1: PA (2 cols) + PB (1 col) per thread (ILP-3)
        {
            double a0 = 0, a1 = 0, b0 = 0;
            for (int k = 0; k < NS; ++k) {
                const double p = sP[pi][k];
                a0 += p * (double)sA[k][pj0 + 0];
                a1 += p * (double)sA[k][pj0 + 1];
                b0 += p * (double)sB[k][pb];
            }
            sPA[pi][pj0 + 0] = a0; sPA[pi][pj0 + 1] = a1;
            sPB[pi][pb] = b0;
        }
        __syncthreads();                                   // barrier A

        // phase 2 (overlapped): wave0 -> G^{-1} (register GJ via __shfl);
        //   waves 1-7 (448 thr) -> Hs (512 dots) + Pp triangle (528 dots)
        if (wid == 0) {
            const int ri = lane & 15, cg = lane >> 4, jb = cg * 4;
            double g0 = (double)Ct[(NS + ri) * NA + NS + jb + 0];
            double g1 = (double)Ct[(NS + ri) * NA + NS + jb + 1];
            double g2 = (double)Ct[(NS + ri) * NA + NS + jb + 2];
            double g3 = (double)Ct[(NS + ri) * NA + NS + jb + 3];
            for (int k = 0; k < NS; ++k) {
                const double b = (double)sB[k][ri];
                g0 += b * sPB[k][jb + 0]; g1 += b * sPB[k][jb + 1];
                g2 += b * sPB[k][jb + 2]; g3 += b * sPB[k][jb + 3];
            }
#pragma unroll
            for (int k = 0; k < NI; ++k) {
                const double myslot = ((k & 3) == 0) ? g0 : ((k & 3) == 1) ? g1
                                     : ((k & 3) == 2) ? g2 : g3;
                const int    plv  = k + ((k >> 2) << 4);      // lane of (k,k)
                const double piv  = __shfl(myslot, plv, 64);
                const double cv   = __shfl(myslot, ri + ((k >> 2) << 4), 64); // (ri,k)
                const double pr0  = __shfl(g0, k + (cg << 4), 64);            // (k,jb+j)
                const double pr1  = __shfl(g1, k + (cg << 4), 64);
                const double pr2  = __shfl(g2, k + (cg << 4), 64);
                const double pr3  = __shfl(g3, k + (cg << 4), 64);
                const double ip   = 1.0 / piv;
                const bool   rk   = (ri == k);
                g0 = rk ? ((jb + 0 == k) ? ip : pr0 * ip)
                        : ((jb + 0 == k) ? -cv * ip : g0 - cv * pr0 * ip);
                g1 = rk ? ((jb + 1 == k) ? ip : pr1 * ip)
                        : ((jb + 1 == k) ? -cv * ip : g1 - cv * pr1 * ip);
                g2 = rk ? ((jb + 2 == k) ? ip : pr2 * ip)
                        : ((jb + 2 == k) ? -cv * ip : g2 - cv * pr2 * ip);
                g3 = rk ? ((jb + 3 == k) ? ip : pr3 * ip)
                        : ((jb + 3 == k) ? -cv * ip : g3 - cv * pr3 * ip);
            }
            sGi[ri][jb + 0] = g0; sGi[ri][jb + 1] = g1;
            sGi[ri][jb + 2] = g2; sGi[ri][jb + 3] = g3;
        } else {
            const int e0 = tid - 64;
            for (int e = e0; e < NI * NS; e += 448) {
                const int i = e >> 5, j = e & 31;
                double acc = (double)Ct[j * NA + NS + i];
                for (int k = 0; k < NS; ++k) acc += (double)sB[k][i] * sPA[k][j];
                sHs[i][j] = acc;
            }
            for (int e = e0; e < NTRI; e += 448) {
                const int p = sTri[e];
                const int i = p >> 8, j = p & 255;
                double acc = (double)Ct[i * NA + j];
                for (int k = 0; k < NS; ++k) acc += (double)sA[k][i] * sPA[k][j];
                sPp[i][j] = acc;
                sPp[j][i] = acc;       // symmetric by construction
            }
        }
        __syncthreads();                                   // barrier B

        // phase 3: K = G^{-1} Hs (2 cols per thread, first 256 threads)
        if (tid < 256) {
            double a0 = 0, a1 = 0;
            for (int k = 0; k < NI; ++k) {
                const double g = sGi[ki][k];
                a0 += g * sHs[k][kj0 + 0];
                a1 += g * sHs[k][kj0 + 1];
            }
            sKt[ki][kj0 + 0] = a0; sKt[ki][kj0 + 1] = a1;
            Kall[t * NI * NS + ki * NS + kj0 + 0] = (float)a0;
            Kall[t * NI * NS + ki * NS + kj0 + 1] = (float)a1;
        }
        __syncthreads();                                   // barrier C

        // phase 4: P = Pp - Hs^T K on the upper triangle, write both slots
        for (int e = tid; e < NTRI; e += 512) {
            const int p = sTri[e];
            const int i = p >> 8, j = p & 255;
            double a = sPp[i][j];
            for (int k = 0; k < NI; ++k) a -= sHs[k][i] * sKt[k][j];
            sP[i][j] = a;
            sP[j][i] = a;
            const float af = (float)a;
            Pall[t * NS * NS + i * NS + j] = af;
            Pall[t * NS * NS + j * NS + i] = af;
        }
        __syncthreads();                                   // barrier D
    }

    // ---- forward rollout: tau (x + u), record x trajectory ----
    if (tid < NS) sx[0][tid] = (double)x0g[tid];
    __syncthreads();
    int cur = 0;
    for (int t = 0; t < TT; ++t) {
        if (tid < NS) {
            const float xv = (float)sx[cur][tid];
            sXT[t][tid] = xv;
            out[t * NA + tid] = xv;
        } else if (tid >= 64 && tid < 64 + NI) {
            const int i = tid - 64;
            const float* Kt = Kall + t * NI * NS + i * NS;
            double acc = 0.0;
            for (int k = 0; k < NS; ++k) acc += (double)Kt[k] * sx[cur][k];
            su[i] = -acc;
            out[t * NA + NS + i] = (float)(-acc);
        }
        __syncthreads();
        if (t < TT - 1) {
            if (tid < NS) {
                double acc = 0.0;
                for (int k = 0; k < NS; ++k) acc += (double)sA[tid][k] * sx[cur][k];
                for (int k = 0; k < NI; ++k) acc += (double)sB[tid][k] * su[k];
                sx[cur ^ 1][tid] = acc;
            }
            __syncthreads();
            cur ^= 1;
        }
    }
    __syncthreads();

    // ---- mu pass: mu_t = P_t x_t (2048 parallel dots); mu_0 negated ----
    for (int e = tid; e < TT * NS; e += 512) {
        const int t = e >> 5, i = e & 31;
        const float* Pt = Pall + t * NS * NS + i * NS;
        double acc = 0.0;
        for (int k = 0; k < NS; ++k) acc += (double)Pt[k] * (double)sXT[t][k];
        if (t == 0) acc = -acc;
        out[NA * TT + t * NS + i] = (float)acc;
    }
}

// ---------------- FALLBACK (round-11/12, passing) — if ws_size < 384 KB ----
__launch_bounds__(256, 1)
__global__ void lqr_kernel_fb(const float* __restrict__ Ag,
                              const float* __restrict__ Bg,
                              const float* __restrict__ Cg,
                              const float* __restrict__ x0g,
                              float* __restrict__ out)
{
    __shared__ float  sKh[HT][NI][NS];
    __shared__ float  sXT[TT][NS];
    __shared__ double sA[NS][NS];
    __shared__ double sB[NS][NI];
    __shared__ double sP[NS][NS];
    __shared__ double sPA[NS][NS];
    __shared__ double sPB[NS][NI];
    __shared__ double sHs[NI][NS];
    __shared__ double sKt[NI][NS];
    __shared__ double sGi[NI][NI];
    __shared__ double sPp[NS][NS];
    __shared__ double sx[2][NS];
    __shared__ double su[NI];

    const int tid  = threadIdx.x;
    const int wid  = tid >> 6, lane = tid & 63;
    const int pi   = tid >> 3, pj0 = (tid & 7) * 4, pb0 = (tid & 7) * 2;
    const int ki   = tid >> 4, kj0 = (tid & 15) * 2;

    for (int idx = tid; idx < NS * NS; idx += 256) sA[idx >> 5][idx & 31] = (double)Ag[idx];
    for (int idx = tid; idx < NS * NI; idx += 256) sB[idx >> 4][idx & 15] = (double)Bg[idx];
    __syncthreads();

    auto step = [&](int t, bool storeK, int kbase, bool emitMu) {
        const float* Ct = Cg + t * NA * NA;
        {
            double a0 = 0, a1 = 0, a2 = 0, a3 = 0, b0 = 0, b1 = 0;
            for (int k = 0; k < NS; ++k) {
                const double p = sP[pi][k];
                a0 += p * sA[k][pj0 + 0]; a1 += p * sA[k][pj0 + 1];
                a2 += p * sA[k][pj0 + 2]; a3 += p * sA[k][pj0 + 3];
                b0 += p * sB[k][pb0 + 0]; b1 += p * sB[k][pb0 + 1];
            }
            sPA[pi][pj0 + 0] = a0; sPA[pi][pj0 + 1] = a1;
            sPA[pi][pj0 + 2] = a2; sPA[pi][pj0 + 3] = a3;
            sPB[pi][pb0 + 0] = b0; sPB[pi][pb0 + 1] = b1;
        }
        __syncthreads();
        if (wid == 0) {
            const int ri = lane & 15, cg = lane >> 4, jb = cg * 4;
            double g0 = (double)Ct[(NS + ri) * NA + NS + jb + 0];
            double g1 = (double)Ct[(NS + ri) * NA + NS + jb + 1];
            double g2 = (double)Ct[(NS + ri) * NA + NS + jb + 2];
            double g3 = (double)Ct[(NS + ri) * NA + NS + jb + 3];
            for (int k = 0; k < NS; ++k) {
                const double b = sB[k][ri];
                g0 += b * sPB[k][jb + 0]; g1 += b * sPB[k][jb + 1];
                g2 += b * sPB[k][jb + 2]; g3 += b * sPB[k][jb + 3];
            }
#pragma unroll
            for (int k = 0; k < NI; ++k) {
                const double myslot = ((k & 3) == 0) ? g0 : ((k & 3) == 1) ? g1
                                     : ((k & 3) == 2) ? g2 : g3;
                const int    plv  = k + ((k >> 2) << 4);
                const double piv  = __shfl(myslot, plv, 64);
                const double cv   = __shfl(myslot, ri + ((k >> 2) << 4), 64);
                const double pr0  = __shfl(g0, k + (cg << 4), 64);
                const double pr1  = __shfl(g1, k + (cg << 4), 64);
                const double pr2  = __shfl(g2, k + (cg << 4), 64);
                const double pr3  = __shfl(g3, k + (cg << 4), 64);
                const double ip   = 1.0 / piv;
                const bool   rk   = (ri == k);
                g0 = rk ? ((jb + 0 == k) ? ip : pr0 * ip)
                        : ((jb + 0 == k) ? -cv * ip : g0 - cv * pr0 * ip);
                g1 = rk ? ((jb + 1 == k) ? ip : pr1 * ip)
                        : ((jb + 1 == k) ? -cv * ip : g1 - cv * pr1 * ip);
                g2 = rk ? ((jb + 2 == k) ? ip : pr2 * ip)
                        : ((jb + 2 == k) ? -cv * ip : g2 - cv * pr2 * ip);
                g3 = rk ? ((jb + 3 == k) ? ip : pr3 * ip)
                        : ((jb + 3 == k) ? -cv * ip : g3 - cv * pr3 * ip);
            }
            sGi[ri][jb + 0] = g0; sGi[ri][jb + 1] = g1;
            sGi[ri][jb + 2] = g2; sGi[ri][jb + 3] = g3;
        } else {
            const int e0 = tid - 64;
            for (int e = e0; e < NI * NS; e += 192) {
                const int i = e >> 5, j = e & 31;
                double acc = (double)Ct[j * NA + NS + i];
                for (int k = 0; k < NS; ++k) acc += sB[k][i] * sPA[k][j];
                sHs[i][j] = acc;
            }
            for (int e = e0; e < NS * NS; e += 192) {
                const int i = e >> 5, j = e & 31;
                double acc = (double)Ct[i * NA + j];
                for (int k = 0; k < NS; ++k) acc += sA[k][i] * sPA[k][j];
                sPp[i][j] = acc;
            }
        }
        __syncthreads();
        {
            double a0 = 0, a1 = 0;
            for (int k = 0; k < NI; ++k) {
                const double g = sGi[ki][k];
                a0 += g * sHs[k][kj0 + 0];
                a1 += g * sHs[k][kj0 + 1];
            }
            sKt[ki][kj0 + 0] = a0; sKt[ki][kj0 + 1] = a1;
            if (storeK) {
                sKh[t - kbase][ki][kj0 + 0] = (float)a0;
                sKh[t - kbase][ki][kj0 + 1] = (float)a1;
            }
        }
        __syncthreads();
        {
            double a0 = sPp[pi][pj0 + 0], a1 = sPp[pi][pj0 + 1];
            double a2 = sPp[pi][pj0 + 2], a3 = sPp[pi][pj0 + 3];
            for (int k = 0; k < NI; ++k) {
                const double h = sHs[k][pi];
                a0 -= h * sKt[k][pj0 + 0]; a1 -= h * sKt[k][pj0 + 1];
                a2 -= h * sKt[k][pj0 + 2]; a3 -= h * sKt[k][pj0 + 3];
            }
            double b0 = sPp[pj0 + 0][pi], b1 = sPp[pj0 + 1][pi];
            double b2 = sPp[pj0 + 2][pi], b3 = sPp[pj0 + 3][pi];
            for (int k = 0; k < NI; ++k) {
                const double hk = sKt[k][pi];
                b0 -= sHs[k][pj0 + 0] * hk; b1 -= sHs[k][pj0 + 1] * hk;
                b2 -= sHs[k][pj0 + 2] * hk; b3 -= sHs[k][pj0 + 3] * hk;
            }
            sP[pi][pj0 + 0] = 0.5 * (a0 + b0); sP[pi][pj0 + 1] = 0.5 * (a1 + b1);
            sP[pi][pj0 + 2] = 0.5 * (a2 + b2); sP[pi][pj0 + 3] = 0.5 * (a3 + b3);
        }
        __syncthreads();
        if (emitMu && tid < NS) {
            double acc = 0.0;
            for (int k = 0; k < NS; ++k) acc += sP[tid][k] * (double)sXT[t][k];
            if (t == 0) acc = -acc;
            out[NA * TT + t * NS + tid] = (float)acc;
        }
    };

    auto sweep = [&](int tlo, int klo, int khi, bool emitMu) {
        for (int idx = tid; idx < NS * NS; idx += 256) sP[idx >> 5][idx & 31] = 0.0;
        __syncthreads();
        for (int t = TT - 1; t >= tlo; --t)
            step(t, (t >= klo && t < khi), klo, emitMu);
    };

    int cur = 0;
    auto forward = [&](int t0, int t1, int kbase) {
        for (int t = t0; t < t1; ++t) {
            if (tid < NS) {
                const float xv = (float)sx[cur][tid];
                sXT[t][tid] = xv;
                out[t * NA + tid] = xv;
            } else if (tid >= 64 && tid < 64 + NI) {
                const int i = tid - 64;
                double acc = 0.0;
                for (int k = 0; k < NS; ++k)
                    acc += (double)sKh[t - kbase][i][k] * sx[cur][k];
                su[i] = -acc;
                out[t * NA + NS + i] = (float)(-acc);
            }
            __syncthreads();
            if (t < TT - 1) {
                if (tid < NS) {
                    double acc = 0.0;
                    for (int k = 0; k < NS; ++k) acc += sA[tid][k] * sx[cur][k];
                    for (int k = 0; k < NI; ++k) acc += sB[tid][k] * su[k];
                    sx[cur ^ 1][tid] = acc;
                }
                __syncthreads();
                cur ^= 1;
            }
        }
    };

    sweep(0, 0, HT, false);
    if (tid < NS) sx[0][tid] = (double)x0g[tid];
    __syncthreads();
    forward(0, HT, 0);
    sweep(HT, HT, TT, false);
    forward(HT, TT, HT);
    sweep(0, 0, 0, true);
}

extern "C" void kernel_launch(void* const* d_in, const int* in_sizes, int n_in,
                              void* d_out, int out_size, void* d_ws, size_t ws_size,
                              hipStream_t stream) {
    // Bind by element count (A=1024, B=512, C=147456, x0=32), fallback dict order.
    const float *A = nullptr, *B = nullptr, *C = nullptr, *x0 = nullptr;
    for (int i = 0; i < n_in; ++i) {
        switch (in_sizes[i]) {
            case 1024:   A  = (const float*)d_in[i]; break;
            case 512:    B  = (const float*)d_in[i]; break;
            case 147456: C  = (const float*)d_in[i]; break;
            case 32:     x0 = (const float*)d_in[i]; break;
            default: break;
        }
    }
    if (!A || !B || !C || !x0) {
        A  = (const float*)d_in[0];
        B  = (const float*)d_in[1];
        C  = (const float*)d_in[2];
        x0 = (const float*)d_in[5];
    }

    const size_t need = (size_t)(TT * NI * NS + TT * NS * NS) * sizeof(float); // 384 KB
    if (d_ws != nullptr && ws_size >= need) {
        float* Kall = (float*)d_ws;
        float* Pall = Kall + TT * NI * NS;
        lqr_fast<<<1, 512, 0, stream>>>(A, B, C, x0, (float*)d_out, Kall, Pall);
    } else {
        lqr_kernel_fb<<<1, 256, 0, stream>>>(A, B, C, x0, (float*)d_out);
    }
}